// Round 1
// baseline (980.052 us; speedup 1.0000x reference)
//
#include <hip/hip_runtime.h>

// ---------------------------------------------------------------------------
// RelationalTransformer: B=32 T=4 L=1024 D=1024 H=8 Hd=128 N=15
// out = edge_logits (32*15*15*18 = 129600) ++ energy (32)   [fp32]
//
// Algebraic restructure (exact up to fp reassociation):
//   scores[b,h,n,l] = (1/sqrt(128)) * qW[b,n,h,:] . v_f[b,l,:]
//       qW[b,n,h,e] = sum_d q[b,n,h*128+d] * Wk[h*128+d, e]
//   (q . bk term is constant over l -> cancels in softmax -> dropped)
//   ctx[b,n,h*128+d] = ctxf[b,nh,:] . Wv[h*128+d,:] + bv[h*128+d]
//       ctxf[b,nh,e] = sum_l attn[b,nh,l] * v_f[b,l,e]   (attn sums to 1)
// ---------------------------------------------------------------------------

#define DEV_INLINE __device__ __forceinline__

// ---------------- generic strided-batched fp32 GEMM:  C = alpha*A@op(B) + bias
// A: M x K row-major (lda)
// BT=true : B is N x K row-major (ldb)  -> C = A @ B^T
// BT=false: B is K x N row-major (ldb)  -> C = A @ B
// batch z = z1*batch2 + z2 ; per-operand strides (s*1, s*2)
template <int BM, int BN, int BK, int TM, int TN, bool BT>
__global__ __launch_bounds__(256) void gemm_k(
    const float* __restrict__ A, const float* __restrict__ B,
    const float* __restrict__ bias, float* __restrict__ C,
    int M, int N, int K, int lda, int ldb, int ldc,
    long sA1, long sB1, long sC1, long sb1,
    int batch2, long sA2, long sB2, long sC2, long sb2,
    float alpha)
{
    const int z  = blockIdx.z;
    const int z1 = z / batch2, z2 = z % batch2;
    A += z1 * sA1 + z2 * sA2;
    B += z1 * sB1 + z2 * sB2;
    C += z1 * sC1 + z2 * sC2;
    const float* bp = bias ? (bias + z1 * sb1 + z2 * sb2) : nullptr;

    const int m0 = blockIdx.y * BM;
    const int n0 = blockIdx.x * BN;

    __shared__ float As[BK * BM];
    __shared__ float Bs[BK * BN];

    const int t   = threadIdx.x;
    const int TNW = BN / TN;             // threads along n
    const int tn  = t % TNW;
    const int tm  = t / TNW;

    float acc[TM][TN];
#pragma unroll
    for (int i = 0; i < TM; ++i)
#pragma unroll
        for (int j = 0; j < TN; ++j) acc[i][j] = 0.0f;

    for (int k0 = 0; k0 < K; k0 += BK) {
        // ---- stage A tile (BM x BK) -> As[k][m]
        constexpr int ACH = BM * BK / 4;
        for (int c = t; c < ACH; c += 256) {
            const int flat = c * 4;
            const int kq = flat % BK, m = flat / BK;
            float4 v = make_float4(0.f, 0.f, 0.f, 0.f);
            if (m0 + m < M)
                v = *(const float4*)&A[(long)(m0 + m) * lda + k0 + kq];
            As[(kq + 0) * BM + m] = v.x;
            As[(kq + 1) * BM + m] = v.y;
            As[(kq + 2) * BM + m] = v.z;
            As[(kq + 3) * BM + m] = v.w;
        }
        // ---- stage B tile -> Bs[k][n]   (N always divisible by BN here)
        constexpr int BCH = BN * BK / 4;
        if constexpr (BT) {
            for (int c = t; c < BCH; c += 256) {
                const int flat = c * 4;
                const int kq = flat % BK, n = flat / BK;
                float4 v = *(const float4*)&B[(long)(n0 + n) * ldb + k0 + kq];
                Bs[(kq + 0) * BN + n] = v.x;
                Bs[(kq + 1) * BN + n] = v.y;
                Bs[(kq + 2) * BN + n] = v.z;
                Bs[(kq + 3) * BN + n] = v.w;
            }
        } else {
            for (int c = t; c < BCH; c += 256) {
                const int flat = c * 4;
                const int n = flat % BN, kq = flat / BN;
                float4 v = *(const float4*)&B[(long)(k0 + kq) * ldb + n0 + n];
                *(float4*)&Bs[kq * BN + n] = v;
            }
        }
        __syncthreads();

#pragma unroll
        for (int kk = 0; kk < BK; ++kk) {
            float a[TM], bv[TN];
            if constexpr (TM == 4) {
                float4 v = *(const float4*)&As[kk * BM + tm * 4];
                a[0] = v.x; a[1] = v.y; a[2] = v.z; a[3] = v.w;
            } else {
#pragma unroll
                for (int i = 0; i < TM; ++i) a[i] = As[kk * BM + tm * TM + i];
            }
            if constexpr (TN == 4) {
                float4 v = *(const float4*)&Bs[kk * BN + tn * 4];
                bv[0] = v.x; bv[1] = v.y; bv[2] = v.z; bv[3] = v.w;
            } else {
#pragma unroll
                for (int j = 0; j < TN; ++j) bv[j] = Bs[kk * BN + tn * TN + j];
            }
#pragma unroll
            for (int i = 0; i < TM; ++i)
#pragma unroll
                for (int j = 0; j < TN; ++j) acc[i][j] += a[i] * bv[j];
        }
        __syncthreads();
    }

#pragma unroll
    for (int i = 0; i < TM; ++i) {
        const int m = m0 + tm * TM + i;
        if (m >= M) continue;
#pragma unroll
        for (int j = 0; j < TN; ++j) {
            const int n = n0 + tn * TN + j;
            float v = acc[i][j] * alpha;
            if (bp) v += bp[n];
            C[(long)m * ldc + n] = v;
        }
    }
}

// ---------------- query[b,n,d] = emb[max(node,0)][d] + bboxes . Wb[d,:] + bb[d]
__global__ __launch_bounds__(256) void build_query_k(
    const int* __restrict__ nodes, const float* __restrict__ bboxes,
    const float* __restrict__ emb, const float* __restrict__ Wb,
    const float* __restrict__ bb, float* __restrict__ query)
{
    const int blk = blockIdx.x;            // b*15 + n
    const int node = nodes[blk];
    const int idx = node < 0 ? 0 : node;
    const float4 bx = *(const float4*)&bboxes[blk * 4];
    const float* er = emb + (long)idx * 1024;
    for (int d = threadIdx.x; d < 1024; d += 256) {
        const float4 w = *(const float4*)&Wb[d * 4];
        query[(long)blk * 1024 + d] =
            er[d] + bb[d] + bx.x * w.x + bx.y * w.y + bx.z * w.z + bx.w * w.w;
    }
}

// ---------------- row softmax over 1024 (in place). one block per row.
__global__ __launch_bounds__(256) void softmax_k(float* __restrict__ sc)
{
    __shared__ float red[4];
    float* p = sc + (long)blockIdx.x * 1024;
    const int t = threadIdx.x;
    float4 v = *(const float4*)&p[t * 4];

    float m = fmaxf(fmaxf(v.x, v.y), fmaxf(v.z, v.w));
#pragma unroll
    for (int o = 32; o; o >>= 1) m = fmaxf(m, __shfl_xor(m, o));
    if ((t & 63) == 0) red[t >> 6] = m;
    __syncthreads();
    m = fmaxf(fmaxf(red[0], red[1]), fmaxf(red[2], red[3]));
    __syncthreads();

    v.x = __expf(v.x - m); v.y = __expf(v.y - m);
    v.z = __expf(v.z - m); v.w = __expf(v.w - m);
    float s = v.x + v.y + v.z + v.w;
#pragma unroll
    for (int o = 32; o; o >>= 1) s += __shfl_xor(s, o);
    if ((t & 63) == 0) red[t >> 6] = s;
    __syncthreads();
    s = red[0] + red[1] + red[2] + red[3];
    const float inv = 1.0f / s;
    v.x *= inv; v.y *= inv; v.z *= inv; v.w *= inv;
    *(float4*)&p[t * 4] = v;
}

// ---------------- edge head: one block per b.
// pair[i,j,u] = relu(hi[i,u] + hj[j,u])  (b1 folded into hi)
// out[b,i,j,c] = pair . W2[c,:] + b2[c]
__global__ __launch_bounds__(256) void edge_k(
    const float* __restrict__ hi, const float* __restrict__ hj,
    const float* __restrict__ W2, const float* __restrict__ b2,
    float* __restrict__ out)
{
    const int b = blockIdx.x;
    const int t = threadIdx.x;
    __shared__ float his[15 * 513];
    __shared__ float hjs[15 * 513];
    for (int idx = t; idx < 15 * 512; idx += 256) {
        const int r = idx >> 9, c = idx & 511;
        his[r * 513 + c] = hi[(long)(b * 15 + r) * 512 + c];
        hjs[r * 513 + c] = hj[(long)(b * 15 + r) * 512 + c];
    }
    __syncthreads();
    if (t < 225) {
        const int i = t / 15, j = t % 15;
        float acc[18];
#pragma unroll
        for (int c = 0; c < 18; ++c) acc[c] = 0.0f;
        const float* hr = &his[i * 513];
        const float* hc = &hjs[j * 513];
        for (int u = 0; u < 512; ++u) {
            float p = hr[u] + hc[u];
            p = p > 0.0f ? p : 0.0f;
#pragma unroll
            for (int c = 0; c < 18; ++c) acc[c] += p * W2[c * 512 + u];
        }
        float* o = out + (long)b * 4050 + t * 18;
#pragma unroll
        for (int c = 0; c < 18; ++c) o[c] = acc[c] + b2[c];
    }
}

// ---------------- energy head: one block per b.
__global__ __launch_bounds__(256) void energy_k(
    const float* __restrict__ enr, const int* __restrict__ nodes,
    const float* __restrict__ Wh1, const float* __restrict__ bh1,
    const float* __restrict__ Wh2, const float* __restrict__ bh2,
    float* __restrict__ out)
{
    const int b = blockIdx.x;
    const int t = threadIdx.x;
    __shared__ float gf[1024];
    __shared__ float hid[256];
    __shared__ float red[4];

    int cnt = 0;
#pragma unroll
    for (int n = 0; n < 15; ++n) cnt += (nodes[b * 15 + n] != -1) ? 1 : 0;
    const float inv_valid = 1.0f / fmaxf((float)cnt, 1.0f);

    for (int e = t; e < 1024; e += 256) {
        float s = 0.0f;
        for (int n = 0; n < 15; ++n) {
            const bool ok = nodes[b * 15 + n] != -1;
            s += ok ? enr[(long)(b * 15 + n) * 1024 + e] : 0.0f;
        }
        gf[e] = s * inv_valid;
    }
    __syncthreads();

    const int wave = t >> 6, lane = t & 63;
    for (int u = wave; u < 256; u += 4) {
        float s = 0.0f;
        for (int e = lane; e < 1024; e += 64) s += gf[e] * Wh1[(long)u * 1024 + e];
#pragma unroll
        for (int o = 32; o; o >>= 1) s += __shfl_xor(s, o);
        if (lane == 0) hid[u] = fmaxf(s + bh1[u], 0.0f);
    }
    __syncthreads();

    float v = hid[t] * Wh2[t];
#pragma unroll
    for (int o = 32; o; o >>= 1) v += __shfl_xor(v, o);
    if ((t & 63) == 0) red[t >> 6] = v;
    __syncthreads();
    if (t == 0) out[129600 + b] = red[0] + red[1] + red[2] + red[3] + bh2[0];
}

// ---------------------------------------------------------------------------
extern "C" void kernel_launch(void* const* d_in, const int* in_sizes, int n_in,
                              void* d_out, int out_size, void* d_ws, size_t ws_size,
                              hipStream_t stream)
{
    const float* visual = (const float*)d_in[0];
    const int*   nodes  = (const int*)  d_in[1];
    const float* bboxes = (const float*)d_in[2];
    const float* emb    = (const float*)d_in[3];
    const float* Wb     = (const float*)d_in[4];
    const float* bb     = (const float*)d_in[5];
    const float* Wq     = (const float*)d_in[6];
    const float* bq     = (const float*)d_in[7];
    const float* Wk     = (const float*)d_in[8];
    /* bk (d_in[9]) cancels in softmax */
    const float* Wv     = (const float*)d_in[10];
    const float* bv     = (const float*)d_in[11];
    const float* Wo     = (const float*)d_in[12];
    const float* bo     = (const float*)d_in[13];
    const float* W1     = (const float*)d_in[14];
    const float* b1     = (const float*)d_in[15];
    const float* W2     = (const float*)d_in[16];
    const float* b2     = (const float*)d_in[17];
    const float* Wh1    = (const float*)d_in[18];
    const float* bh1    = (const float*)d_in[19];
    const float* Wh2    = (const float*)d_in[20];
    const float* bh2    = (const float*)d_in[21];

    float* out = (float*)d_out;
    float* ws  = (float*)d_ws;

    // workspace layout (floats)
    float* query  = ws;                 // 480*1024      = 491520
    float* q      = ws + 491520;        // 480*1024      = 491520
    float* qW     = ws + 983040;        // 32*120*1024   = 3932160  (reused as ctxf)
    float* scores = ws + 4915200;       // 32*120*1024   = 3932160
    float* ctx    = ws + 8847360;       // 480*1024      = 491520
    float* enr    = ws + 9338880;       // 480*1024      = 491520
    float* hi     = ws + 9830400;       // 480*512       = 245760
    float* hj     = ws + 10076160;      // 480*512       = 245760
    float* ctxf   = qW;                 // alias: qW dead after scores GEMM

    const float inv_sqrt_hd = 0.08838834764831845f;  // 1/sqrt(128)
    const float* v_f = visual + 3 * 1048576;         // frame T-1; batch stride 4*1048576

    // 1) query
    build_query_k<<<480, 256, 0, stream>>>(nodes, bboxes, emb, Wb, bb, query);

    // 2) q = query @ Wq^T + bq            (480 x 1024, K=1024)
    gemm_k<64, 64, 16, 4, 4, true><<<dim3(16, 8, 1), 256, 0, stream>>>(
        query, Wq, bq, q, 480, 1024, 1024, 1024, 1024, 1024,
        0, 0, 0, 0, 1, 0, 0, 0, 0, 1.0f);

    // 3) qW[h] = q[:, h*128:(h+1)*128] @ Wk[h*128:(h+1)*128, :] * inv_sqrt_hd
    //    C rows stride 8192 (=(n,h) layout), batch over h
    gemm_k<64, 64, 16, 4, 4, false><<<dim3(16, 8, 8), 256, 0, stream>>>(
        q, Wk, nullptr, qW, 480, 1024, 128, 1024, 1024, 8192,
        128, 131072, 1024, 0, 1, 0, 0, 0, 0, inv_sqrt_hd);

    // 4) scores[b] = qW[b] @ v_f[b]^T      (120 x 1024, K=1024), batch over b
    gemm_k<64, 64, 16, 4, 4, true><<<dim3(16, 2, 32), 256, 0, stream>>>(
        qW, v_f, nullptr, scores, 120, 1024, 1024, 1024, 1024, 1024,
        122880, 4194304, 122880, 0, 1, 0, 0, 0, 0, 1.0f);

    // 5) softmax over l (3840 rows of 1024)
    softmax_k<<<3840, 256, 0, stream>>>(scores);

    // 6) ctxf[b] = attn[b] @ v_f[b]        (120 x 1024, K=1024), batch over b
    gemm_k<64, 64, 16, 4, 4, false><<<dim3(16, 2, 32), 256, 0, stream>>>(
        scores, v_f, nullptr, ctxf, 120, 1024, 1024, 1024, 1024, 1024,
        122880, 4194304, 122880, 0, 1, 0, 0, 0, 0, 1.0f);

    // 7) ctx[b,:,h] = ctxf[b,(:,h),:] @ Wv_h^T + bv_h   (15 x 128, K=1024), batch (b,h)
    gemm_k<16, 64, 32, 1, 4, true><<<dim3(2, 1, 256), 256, 0, stream>>>(
        ctxf, Wv, bv, ctx, 15, 128, 1024, 8192, 1024, 1024,
        122880, 0, 15360, 0, 8, 1024, 131072, 128, 128, 1.0f);

    // 8) enriched = ctx @ Wo^T + bo        (480 x 1024, K=1024)
    gemm_k<64, 64, 16, 4, 4, true><<<dim3(16, 8, 1), 256, 0, stream>>>(
        ctx, Wo, bo, enr, 480, 1024, 1024, 1024, 1024, 1024,
        0, 0, 0, 0, 1, 0, 0, 0, 0, 1.0f);

    // 9) hi = enr @ W1[:, :1024]^T + b1 ;  hj = enr @ W1[:, 1024:]^T
    gemm_k<64, 64, 16, 4, 4, true><<<dim3(8, 8, 1), 256, 0, stream>>>(
        enr, W1, b1, hi, 480, 512, 1024, 1024, 2048, 512,
        0, 0, 0, 0, 1, 0, 0, 0, 0, 1.0f);
    gemm_k<64, 64, 16, 4, 4, true><<<dim3(8, 8, 1), 256, 0, stream>>>(
        enr, W1 + 1024, nullptr, hj, 480, 512, 1024, 1024, 2048, 512,
        0, 0, 0, 0, 1, 0, 0, 0, 0, 1.0f);

    // 10) edge logits -> out[0 .. 129600)
    edge_k<<<32, 256, 0, stream>>>(hi, hj, W2, b2, out);

    // 11) energy -> out[129600 .. 129632)
    energy_k<<<32, 256, 0, stream>>>(enr, nodes, Wh1, bh1, Wh2, bh2, out);
}

// Round 3
// 618.182 us; speedup vs baseline: 1.5854x; 1.5854x over previous
//
#include <hip/hip_runtime.h>

// ---------------------------------------------------------------------------
// RelationalTransformer: B=32 T=4 L=1024 D=1024 H=8 Hd=128 N=15
// out = edge_logits (32*15*15*18 = 129600) ++ energy (32)   [fp32]
//
// Algebraic restructure (exact up to fp reassociation):
//   scores[b,h,n,l] = (1/sqrt(128)) * qW[b,n,h,:] . v_f[b,l,:]
//       qW[b,n,h,e] = sum_d q[b,n,h*128+d] * Wk[h*128+d, e]
//   (q . bk term is constant over l -> cancels in softmax -> dropped)
//   ctx[b,n,h*128+d] = ctxf[b,nh,:] . Wv[h*128+d,:] + bv[h*128+d]
//       ctxf[b,nh,e] = sum_l attn[b,nh,l] * v_f[b,l,e]   (attn sums to 1)
// ---------------------------------------------------------------------------

// ---------------- generic strided-batched fp32 GEMM:  C = alpha*A@op(B) + bias
template <int BM, int BN, int BK, int TM, int TN, bool BT>
__global__ __launch_bounds__(256) void gemm_k(
    const float* __restrict__ A, const float* __restrict__ B,
    const float* __restrict__ bias, float* __restrict__ C,
    int M, int N, int K, int lda, int ldb, int ldc,
    long sA1, long sB1, long sC1, long sb1,
    int batch2, long sA2, long sB2, long sC2, long sb2,
    float alpha)
{
    const int z  = blockIdx.z;
    const int z1 = z / batch2, z2 = z % batch2;
    A += z1 * sA1 + z2 * sA2;
    B += z1 * sB1 + z2 * sB2;
    C += z1 * sC1 + z2 * sC2;
    const float* bp = bias ? (bias + z1 * sb1 + z2 * sb2) : nullptr;

    const int m0 = blockIdx.y * BM;
    const int n0 = blockIdx.x * BN;

    __shared__ float As[BK * BM];
    __shared__ float Bs[BK * BN];

    const int t   = threadIdx.x;
    const int TNW = BN / TN;
    const int tn  = t % TNW;
    const int tm  = t / TNW;

    float acc[TM][TN];
#pragma unroll
    for (int i = 0; i < TM; ++i)
#pragma unroll
        for (int j = 0; j < TN; ++j) acc[i][j] = 0.0f;

    for (int k0 = 0; k0 < K; k0 += BK) {
        constexpr int ACH = BM * BK / 4;
        for (int c = t; c < ACH; c += 256) {
            const int flat = c * 4;
            const int kq = flat % BK, m = flat / BK;
            float4 v = make_float4(0.f, 0.f, 0.f, 0.f);
            if (m0 + m < M)
                v = *(const float4*)&A[(long)(m0 + m) * lda + k0 + kq];
            As[(kq + 0) * BM + m] = v.x;
            As[(kq + 1) * BM + m] = v.y;
            As[(kq + 2) * BM + m] = v.z;
            As[(kq + 3) * BM + m] = v.w;
        }
        constexpr int BCH = BN * BK / 4;
        if constexpr (BT) {
            for (int c = t; c < BCH; c += 256) {
                const int flat = c * 4;
                const int kq = flat % BK, n = flat / BK;
                float4 v = *(const float4*)&B[(long)(n0 + n) * ldb + k0 + kq];
                Bs[(kq + 0) * BN + n] = v.x;
                Bs[(kq + 1) * BN + n] = v.y;
                Bs[(kq + 2) * BN + n] = v.z;
                Bs[(kq + 3) * BN + n] = v.w;
            }
        } else {
            for (int c = t; c < BCH; c += 256) {
                const int flat = c * 4;
                const int n = flat % BN, kq = flat / BN;
                float4 v = *(const float4*)&B[(long)(k0 + kq) * ldb + n0 + n];
                *(float4*)&Bs[kq * BN + n] = v;
            }
        }
        __syncthreads();

#pragma unroll
        for (int kk = 0; kk < BK; ++kk) {
            float a[TM], bvv[TN];
            if constexpr (TM == 4) {
                float4 v = *(const float4*)&As[kk * BM + tm * 4];
                a[0] = v.x; a[1] = v.y; a[2] = v.z; a[3] = v.w;
            } else {
#pragma unroll
                for (int i = 0; i < TM; ++i) a[i] = As[kk * BM + tm * TM + i];
            }
            if constexpr (TN == 4) {
                float4 v = *(const float4*)&Bs[kk * BN + tn * 4];
                bvv[0] = v.x; bvv[1] = v.y; bvv[2] = v.z; bvv[3] = v.w;
            } else {
#pragma unroll
                for (int j = 0; j < TN; ++j) bvv[j] = Bs[kk * BN + tn * TN + j];
            }
#pragma unroll
            for (int i = 0; i < TM; ++i)
#pragma unroll
                for (int j = 0; j < TN; ++j) acc[i][j] += a[i] * bvv[j];
        }
        __syncthreads();
    }

#pragma unroll
    for (int i = 0; i < TM; ++i) {
        const int m = m0 + tm * TM + i;
        if (m >= M) continue;
#pragma unroll
        for (int j = 0; j < TN; ++j) {
            const int n = n0 + tn * TN + j;
            float v = acc[i][j] * alpha;
            if (bp) v += bp[n];
            C[(long)m * ldc + n] = v;
        }
    }
}

// ---------------- query[b,n,d] = emb[max(node,0)][d] + bboxes . Wb[d,:] + bb[d]
__global__ __launch_bounds__(256) void build_query_k(
    const int* __restrict__ nodes, const float* __restrict__ bboxes,
    const float* __restrict__ emb, const float* __restrict__ Wb,
    const float* __restrict__ bb, float* __restrict__ query)
{
    const int blk = blockIdx.x;
    const int node = nodes[blk];
    const int idx = node < 0 ? 0 : node;
    const float4 bx = *(const float4*)&bboxes[blk * 4];
    const float* er = emb + (long)idx * 1024;
    for (int d = threadIdx.x; d < 1024; d += 256) {
        const float4 w = *(const float4*)&Wb[d * 4];
        query[(long)blk * 1024 + d] =
            er[d] + bb[d] + bx.x * w.x + bx.y * w.y + bx.z * w.z + bx.w * w.w;
    }
}

// ---------------- row softmax over 1024 (in place). one block per row.
__global__ __launch_bounds__(256) void softmax_k(float* __restrict__ sc)
{
    __shared__ float red[4];
    float* p = sc + (long)blockIdx.x * 1024;
    const int t = threadIdx.x;
    float4 v = *(const float4*)&p[t * 4];

    float m = fmaxf(fmaxf(v.x, v.y), fmaxf(v.z, v.w));
#pragma unroll
    for (int o = 32; o; o >>= 1) m = fmaxf(m, __shfl_xor(m, o));
    if ((t & 63) == 0) red[t >> 6] = m;
    __syncthreads();
    m = fmaxf(fmaxf(red[0], red[1]), fmaxf(red[2], red[3]));
    __syncthreads();

    v.x = __expf(v.x - m); v.y = __expf(v.y - m);
    v.z = __expf(v.z - m); v.w = __expf(v.w - m);
    float s = v.x + v.y + v.z + v.w;
#pragma unroll
    for (int o = 32; o; o >>= 1) s += __shfl_xor(s, o);
    if ((t & 63) == 0) red[t >> 6] = s;
    __syncthreads();
    s = red[0] + red[1] + red[2] + red[3];
    const float inv = 1.0f / s;
    v.x *= inv; v.y *= inv; v.z *= inv; v.w *= inv;
    *(float4*)&p[t * 4] = v;
}

// ---------------- edge head: one block per (b, i). thread = (j, c).
// LDS stages hj-chunk and W2-chunk with +1-padded stride (18 distinct c rows
// at stride 256 would alias to one bank; stride 257 spreads them).
__global__ __launch_bounds__(320) void edge_k(
    const float* __restrict__ hi, const float* __restrict__ hj,
    const float* __restrict__ W2, const float* __restrict__ b2,
    float* __restrict__ out)
{
    const int b = blockIdx.x, i = blockIdx.y;
    const int t = threadIdx.x;
    __shared__ float hiS[256];
    __shared__ float hjS[15][257];
    __shared__ float w2S[18][257];
    const int j = t / 18, c = t % 18;       // valid when t < 270
    float acc = 0.0f;

    for (int u0 = 0; u0 < 512; u0 += 256) {
        __syncthreads();
        if (t < 64) {
            float4 v = *(const float4*)&hi[(long)(b * 15 + i) * 512 + u0 + t * 4];
            hiS[t * 4 + 0] = v.x; hiS[t * 4 + 1] = v.y;
            hiS[t * 4 + 2] = v.z; hiS[t * 4 + 3] = v.w;
        }
        for (int x = t; x < 960; x += 320) {          // 15 * 256 / 4
            const int r = x >> 6, cc = (x & 63) * 4;
            float4 v = *(const float4*)&hj[(long)(b * 15 + r) * 512 + u0 + cc];
            hjS[r][cc + 0] = v.x; hjS[r][cc + 1] = v.y;
            hjS[r][cc + 2] = v.z; hjS[r][cc + 3] = v.w;
        }
        for (int x = t; x < 1152; x += 320) {         // 18 * 256 / 4
            const int r = x >> 6, cc = (x & 63) * 4;
            float4 v = *(const float4*)&W2[(long)r * 512 + u0 + cc];
            w2S[r][cc + 0] = v.x; w2S[r][cc + 1] = v.y;
            w2S[r][cc + 2] = v.z; w2S[r][cc + 3] = v.w;
        }
        __syncthreads();
        if (t < 270) {
            for (int u = 0; u < 256; ++u) {
                float p = hiS[u] + hjS[j][u];
                p = p > 0.0f ? p : 0.0f;
                acc += p * w2S[c][u];
            }
        }
    }
    if (t < 270)
        out[((long)(b * 15 + i) * 15 + j) * 18 + c] = acc + b2[c];
}

// ---------------- energy stage 1: gfeat[b][e] = masked mean over nodes
__global__ __launch_bounds__(256) void energy1_k(
    const float* __restrict__ enr, const int* __restrict__ nodes,
    float* __restrict__ gfeat)
{
    const int b = blockIdx.y;
    const int e = blockIdx.x * 256 + threadIdx.x;
    int cnt = 0;
#pragma unroll
    for (int n = 0; n < 15; ++n) cnt += (nodes[b * 15 + n] != -1) ? 1 : 0;
    const float inv_valid = 1.0f / fmaxf((float)cnt, 1.0f);
    float s = 0.0f;
#pragma unroll
    for (int n = 0; n < 15; ++n) {
        const bool ok = nodes[b * 15 + n] != -1;
        s += ok ? enr[(long)(b * 15 + n) * 1024 + e] : 0.0f;
    }
    gfeat[b * 1024 + e] = s * inv_valid;
}

// ---------------- energy stage 2: hidr[b][u] = relu(gfeat.Wh1[u]+bh1)*Wh2[u]
// grid (16, 32): block covers 16 hidden units of one batch; wave per 4 units.
__global__ __launch_bounds__(256) void energy2_k(
    const float* __restrict__ gfeat, const float* __restrict__ Wh1,
    const float* __restrict__ bh1, const float* __restrict__ Wh2,
    float* __restrict__ hidr)
{
    const int b  = blockIdx.y;
    const int u0 = blockIdx.x * 16;
    const int t = threadIdx.x;
    __shared__ float gf[1024];
    {
        float4 v = *(const float4*)&gfeat[b * 1024 + t * 4];
        gf[t * 4 + 0] = v.x; gf[t * 4 + 1] = v.y;
        gf[t * 4 + 2] = v.z; gf[t * 4 + 3] = v.w;
    }
    __syncthreads();
    const int wave = t >> 6, lane = t & 63;
#pragma unroll
    for (int r = 0; r < 4; ++r) {
        const int u = u0 + wave * 4 + r;
        float s = 0.0f;
#pragma unroll
        for (int e0 = 0; e0 < 1024; e0 += 64)
            s += gf[e0 + lane] * Wh1[(long)u * 1024 + e0 + lane];
#pragma unroll
        for (int o = 32; o; o >>= 1) s += __shfl_xor(s, o);
        if (lane == 0)
            hidr[b * 256 + u] = fmaxf(s + bh1[u], 0.0f) * Wh2[u];
    }
}

// ---------------- energy stage 3: out[b] = sum_u hidr[b][u] + bh2
__global__ __launch_bounds__(256) void energy3_k(
    const float* __restrict__ hidr, const float* __restrict__ bh2,
    float* __restrict__ out)
{
    const int b = blockIdx.x;
    const int t = threadIdx.x;
    __shared__ float red[4];
    float v = hidr[b * 256 + t];
#pragma unroll
    for (int o = 32; o; o >>= 1) v += __shfl_xor(v, o);
    if ((t & 63) == 0) red[t >> 6] = v;
    __syncthreads();
    if (t == 0) out[129600 + b] = red[0] + red[1] + red[2] + red[3] + bh2[0];
}

// ---------------------------------------------------------------------------
extern "C" void kernel_launch(void* const* d_in, const int* in_sizes, int n_in,
                              void* d_out, int out_size, void* d_ws, size_t ws_size,
                              hipStream_t stream)
{
    const float* visual = (const float*)d_in[0];
    const int*   nodes  = (const int*)  d_in[1];
    const float* bboxes = (const float*)d_in[2];
    const float* emb    = (const float*)d_in[3];
    const float* Wb     = (const float*)d_in[4];
    const float* bb     = (const float*)d_in[5];
    const float* Wq     = (const float*)d_in[6];
    const float* bq     = (const float*)d_in[7];
    const float* Wk     = (const float*)d_in[8];
    /* bk (d_in[9]) cancels in softmax */
    const float* Wv     = (const float*)d_in[10];
    const float* bv     = (const float*)d_in[11];
    const float* Wo     = (const float*)d_in[12];
    const float* bo     = (const float*)d_in[13];
    const float* W1     = (const float*)d_in[14];
    const float* b1     = (const float*)d_in[15];
    const float* W2     = (const float*)d_in[16];
    const float* b2     = (const float*)d_in[17];
    const float* Wh1    = (const float*)d_in[18];
    const float* bh1    = (const float*)d_in[19];
    const float* Wh2    = (const float*)d_in[20];
    const float* bh2    = (const float*)d_in[21];

    float* out = (float*)d_out;
    float* ws  = (float*)d_ws;

    // workspace layout (floats)
    float* query  = ws;                 // 480*1024
    float* q      = ws + 491520;        // 480*1024
    float* qW     = ws + 983040;        // 32*120*1024 (reused as ctxf)
    float* scores = ws + 4915200;       // 32*120*1024
    float* ctx    = ws + 8847360;       // 480*1024
    float* enr    = ws + 9338880;       // 480*1024
    float* hi     = ws + 9830400;       // 480*512
    float* hj     = ws + 10076160;      // 480*512
    float* ctxf   = qW;                 // alias: qW dead after scores GEMM
    float* gfeat  = query;              // alias: query dead after q GEMM
    float* hidr   = query + 32768;      // alias

    const float inv_sqrt_hd = 0.08838834764831845f;  // 1/sqrt(128)
    const float* v_f = visual + 3 * 1048576;         // frame T-1; batch stride 4*1048576

    // 1) query
    build_query_k<<<480, 256, 0, stream>>>(nodes, bboxes, emb, Wb, bb, query);

    // 2) q = query @ Wq^T + bq            (480 x 1024, K=1024)
    gemm_k<64, 64, 16, 4, 4, true><<<dim3(16, 8, 1), 256, 0, stream>>>(
        query, Wq, bq, q, 480, 1024, 1024, 1024, 1024, 1024,
        0, 0, 0, 0, 1, 0, 0, 0, 0, 1.0f);

    // 3) qW[h] = q[:, h-slice] @ Wk[h-slice, :] * inv_sqrt_hd
    gemm_k<64, 64, 16, 4, 4, false><<<dim3(16, 8, 8), 256, 0, stream>>>(
        q, Wk, nullptr, qW, 480, 1024, 128, 1024, 1024, 8192,
        128, 131072, 1024, 0, 1, 0, 0, 0, 0, inv_sqrt_hd);

    // 4) scores[b] = qW[b] @ v_f[b]^T      (120 x 1024, K=1024)
    gemm_k<64, 64, 16, 4, 4, true><<<dim3(16, 2, 32), 256, 0, stream>>>(
        qW, v_f, nullptr, scores, 120, 1024, 1024, 1024, 1024, 1024,
        122880, 4194304, 122880, 0, 1, 0, 0, 0, 0, 1.0f);

    // 5) softmax over l
    softmax_k<<<3840, 256, 0, stream>>>(scores);

    // 6) ctxf[b] = attn[b] @ v_f[b]        (120 x 1024, K=1024)
    gemm_k<64, 64, 16, 4, 4, false><<<dim3(16, 2, 32), 256, 0, stream>>>(
        scores, v_f, nullptr, ctxf, 120, 1024, 1024, 1024, 1024, 1024,
        122880, 4194304, 122880, 0, 1, 0, 0, 0, 0, 1.0f);

    // 7) ctx[b,:,h] = ctxf[b,(:,h),:] @ Wv_h^T + bv_h
    gemm_k<16, 64, 32, 1, 4, true><<<dim3(2, 1, 256), 256, 0, stream>>>(
        ctxf, Wv, bv, ctx, 15, 128, 1024, 8192, 1024, 1024,
        122880, 0, 15360, 0, 8, 1024, 131072, 128, 128, 1.0f);

    // 8) enriched = ctx @ Wo^T + bo        (480 x 1024, K=1024)
    gemm_k<64, 64, 16, 4, 4, true><<<dim3(16, 8, 1), 256, 0, stream>>>(
        ctx, Wo, bo, enr, 480, 1024, 1024, 1024, 1024, 1024,
        0, 0, 0, 0, 1, 0, 0, 0, 0, 1.0f);

    // 9) hi = enr @ W1[:, :1024]^T + b1 ;  hj = enr @ W1[:, 1024:]^T
    gemm_k<64, 64, 16, 4, 4, true><<<dim3(8, 8, 1), 256, 0, stream>>>(
        enr, W1, b1, hi, 480, 512, 1024, 1024, 2048, 512,
        0, 0, 0, 0, 1, 0, 0, 0, 0, 1.0f);
    gemm_k<64, 64, 16, 4, 4, true><<<dim3(8, 8, 1), 256, 0, stream>>>(
        enr, W1 + 1024, nullptr, hj, 480, 512, 1024, 1024, 2048, 512,
        0, 0, 0, 0, 1, 0, 0, 0, 0, 1.0f);

    // 10) edge logits -> out[0 .. 129600)
    edge_k<<<dim3(32, 15, 1), 320, 0, stream>>>(hi, hj, W2, b2, out);

    // 11) energy -> out[129600 .. 129632)
    energy1_k<<<dim3(4, 32, 1), 256, 0, stream>>>(enr, nodes, gfeat);
    energy2_k<<<dim3(16, 32, 1), 256, 0, stream>>>(gfeat, Wh1, bh1, Wh2, hidr);
    energy3_k<<<32, 256, 0, stream>>>(hidr, bh2, out);
}

// Round 5
// 511.878 us; speedup vs baseline: 1.9146x; 1.2077x over previous
//
#include <hip/hip_runtime.h>
#include <type_traits>

// ---------------------------------------------------------------------------
// RelationalTransformer: B=32 T=4 L=1024 D=1024 H=8 Hd=128 N=15
// out = edge_logits (32*15*15*18 = 129600) ++ energy (32)   [fp32]
//
// Restructure:
//   scores[b,(n,h),l] = qW[b,(n,h),:] . v_f[b,l,:]        (bf16 MFMA, K=e)
//   ctxf[b,(n,h),e]   = attn[b,(n,h),:] . v_fT[b,e,:]     (bf16 MFMA, K=l)
//   bk cancels in softmax; bv applied in ctx GEMM epilogue.
// ---------------------------------------------------------------------------

typedef __attribute__((ext_vector_type(8))) short bf16x8;   // 8 bf16 in 4 VGPRs
typedef __attribute__((ext_vector_type(4))) float f32x4;

__device__ __forceinline__ unsigned short f2bf(float f) {   // RNE float->bf16
    unsigned int u = __float_as_uint(f);
    u = u + 0x7FFFu + ((u >> 16) & 1u);
    return (unsigned short)(u >> 16);
}

// ---------------- generic strided-batched fp32 GEMM:  C = alpha*A@op(B) + bias
// OUTBF: write bf16 (ushort) C instead of fp32.
template <int BM, int BN, int BK, int TM, int TN, bool BT, bool OUTBF = false>
__global__ __launch_bounds__(256) void gemm_k(
    const float* __restrict__ A, const float* __restrict__ B,
    const float* __restrict__ bias, void* __restrict__ Cv,
    int M, int N, int K, int lda, int ldb, int ldc,
    long sA1, long sB1, long sC1, long sb1,
    int batch2, long sA2, long sB2, long sC2, long sb2,
    float alpha)
{
    using OutT = typename std::conditional<OUTBF, unsigned short, float>::type;
    const int z  = blockIdx.z;
    const int z1 = z / batch2, z2 = z % batch2;
    A += z1 * sA1 + z2 * sA2;
    B += z1 * sB1 + z2 * sB2;
    OutT* C = ((OutT*)Cv) + z1 * sC1 + z2 * sC2;
    const float* bp = bias ? (bias + z1 * sb1 + z2 * sb2) : nullptr;

    const int m0 = blockIdx.y * BM;
    const int n0 = blockIdx.x * BN;

    __shared__ float As[BK * BM];
    __shared__ float Bs[BK * BN];

    const int t   = threadIdx.x;
    const int TNW = BN / TN;
    const int tn  = t % TNW;
    const int tm  = t / TNW;

    float acc[TM][TN];
#pragma unroll
    for (int i = 0; i < TM; ++i)
#pragma unroll
        for (int j = 0; j < TN; ++j) acc[i][j] = 0.0f;

    for (int k0 = 0; k0 < K; k0 += BK) {
        constexpr int ACH = BM * BK / 4;
        for (int c = t; c < ACH; c += 256) {
            const int flat = c * 4;
            const int kq = flat % BK, m = flat / BK;
            float4 v = make_float4(0.f, 0.f, 0.f, 0.f);
            if (m0 + m < M)
                v = *(const float4*)&A[(long)(m0 + m) * lda + k0 + kq];
            As[(kq + 0) * BM + m] = v.x;
            As[(kq + 1) * BM + m] = v.y;
            As[(kq + 2) * BM + m] = v.z;
            As[(kq + 3) * BM + m] = v.w;
        }
        constexpr int BCH = BN * BK / 4;
        if constexpr (BT) {
            for (int c = t; c < BCH; c += 256) {
                const int flat = c * 4;
                const int kq = flat % BK, n = flat / BK;
                float4 v = *(const float4*)&B[(long)(n0 + n) * ldb + k0 + kq];
                Bs[(kq + 0) * BN + n] = v.x;
                Bs[(kq + 1) * BN + n] = v.y;
                Bs[(kq + 2) * BN + n] = v.z;
                Bs[(kq + 3) * BN + n] = v.w;
            }
        } else {
            for (int c = t; c < BCH; c += 256) {
                const int flat = c * 4;
                const int n = flat % BN, kq = flat / BN;
                float4 v = *(const float4*)&B[(long)(k0 + kq) * ldb + n0 + n];
                *(float4*)&Bs[kq * BN + n] = v;
            }
        }
        __syncthreads();

#pragma unroll
        for (int kk = 0; kk < BK; ++kk) {
            float a[TM], bvv[TN];
            if constexpr (TM == 4) {
                float4 v = *(const float4*)&As[kk * BM + tm * 4];
                a[0] = v.x; a[1] = v.y; a[2] = v.z; a[3] = v.w;
            } else {
#pragma unroll
                for (int i = 0; i < TM; ++i) a[i] = As[kk * BM + tm * TM + i];
            }
            if constexpr (TN == 4) {
                float4 v = *(const float4*)&Bs[kk * BN + tn * 4];
                bvv[0] = v.x; bvv[1] = v.y; bvv[2] = v.z; bvv[3] = v.w;
            } else {
#pragma unroll
                for (int j = 0; j < TN; ++j) bvv[j] = Bs[kk * BN + tn * TN + j];
            }
#pragma unroll
            for (int i = 0; i < TM; ++i)
#pragma unroll
                for (int j = 0; j < TN; ++j) acc[i][j] += a[i] * bvv[j];
        }
        __syncthreads();
    }

#pragma unroll
    for (int i = 0; i < TM; ++i) {
        const int m = m0 + tm * TM + i;
        if (m >= M) continue;
#pragma unroll
        for (int j = 0; j < TN; ++j) {
            const int n = n0 + tn * TN + j;
            float v = acc[i][j] * alpha;
            if (bp) v += bp[n];
            if constexpr (OUTBF)
                C[(long)m * ldc + n] = f2bf(v);
            else
                C[(long)m * ldc + n] = v;
        }
    }
}

// ---------------- bf16 MFMA GEMM: C[m][n] = sum_k A[m][k]*B[n][k]
// A: Mpad x 1024 row-major bf16; B: 1024 x 1024 row-major bf16 (acts as B^T);
// C: fp32 ldc=1024, stores guarded to m < M. Tile 64x128, 4 waves (2x2).
__global__ __launch_bounds__(256) void bfgemm_k(
    const unsigned short* __restrict__ A, const unsigned short* __restrict__ B,
    float* __restrict__ C, int M, long sA, long sB, long sC)
{
    const int b  = blockIdx.z;
    const int m0 = blockIdx.y * 64;
    const int n0 = blockIdx.x * 128;
    const unsigned short* Ab = A + b * sA;
    const unsigned short* Bb = B + b * sB;
    float* Cb = C + b * sC;

    __shared__ __align__(16) unsigned short As[64 * 32];   // [m][k]
    __shared__ __align__(16) unsigned short Bs[128 * 32];  // [n][k]

    const int t    = threadIdx.x;
    const int lane = t & 63;
    const int w    = t >> 6;
    const int wm   = w >> 1, wn = w & 1;       // wave tile: 32 x 64

    f32x4 acc[2][4] = {};

    const int ar = t >> 2;              // staging row (0..63)
    const int ac = (t & 3) * 8;         // staging k-offset (bf16 elems)

    for (int k0 = 0; k0 < 1024; k0 += 32) {
        // global->reg (issued before barrier: latency overlaps prior MFMA)
        uint4 av  = *(const uint4*)(Ab + (long)(m0 + ar) * 1024 + k0 + ac);
        uint4 bv0 = *(const uint4*)(Bb + (long)(n0 + ar) * 1024 + k0 + ac);
        uint4 bv1 = *(const uint4*)(Bb + (long)(n0 + 64 + ar) * 1024 + k0 + ac);
        __syncthreads();                 // prior-iter LDS reads done
        *(uint4*)&As[t * 8]        = av;
        *(uint4*)&Bs[t * 8]        = bv0;
        *(uint4*)&Bs[2048 + t * 8] = bv1;
        __syncthreads();

        const int krow = (lane >> 4) * 8;
        bf16x8 af[2], bf[4];
#pragma unroll
        for (int fi = 0; fi < 2; ++fi)
            af[fi] = *(const bf16x8*)&As[(wm * 32 + fi * 16 + (lane & 15)) * 32 + krow];
#pragma unroll
        for (int fj = 0; fj < 4; ++fj)
            bf[fj] = *(const bf16x8*)&Bs[(wn * 64 + fj * 16 + (lane & 15)) * 32 + krow];
#pragma unroll
        for (int fi = 0; fi < 2; ++fi)
#pragma unroll
            for (int fj = 0; fj < 4; ++fj)
                acc[fi][fj] = __builtin_amdgcn_mfma_f32_16x16x32_bf16(
                    af[fi], bf[fj], acc[fi][fj], 0, 0, 0);
    }

    const int rbase = (lane >> 4) * 4;
    const int cn    = n0 + wn * 64 + (lane & 15);
#pragma unroll
    for (int fi = 0; fi < 2; ++fi) {
        const int mb = m0 + wm * 32 + fi * 16 + rbase;
#pragma unroll
        for (int r = 0; r < 4; ++r) {
            const int m = mb + r;
            if (m < M) {
#pragma unroll
                for (int fj = 0; fj < 4; ++fj)
                    Cb[(long)m * 1024 + cn + fj * 16] = acc[fi][fj][r];
            }
        }
    }
}

// ---------------- fused convert: v_bf[b][l][e] and v_bfT[b][e][l] from fp32
// grid (16 e-tiles, 16 l-tiles, 32 b), 64x64 tile.
// NOTE: visual_feats is (B, T=4, L, D); vf points at frame T-1 of batch 0,
// so the per-batch stride is 4*1048576 (NOT 1048576 — round-4 bug).
__global__ __launch_bounds__(256) void cvt_k(
    const float* __restrict__ vf, unsigned short* __restrict__ vbf,
    unsigned short* __restrict__ vbfT)
{
    const int b  = blockIdx.z;
    const int e0 = blockIdx.x * 64;
    const int l0 = blockIdx.y * 64;
    const float* src = vf + (long)b * 4194304;   // batch stride = T*L*D
    __shared__ unsigned short tile[64][72];
    const int t = threadIdx.x;
    const int r0 = t >> 4, c0 = (t & 15) * 4;
#pragma unroll
    for (int rr = 0; rr < 4; ++rr) {
        const int r = r0 + rr * 16;
        float4 v = *(const float4*)&src[(long)(l0 + r) * 1024 + e0 + c0];
        ushort4 o;
        o.x = f2bf(v.x); o.y = f2bf(v.y); o.z = f2bf(v.z); o.w = f2bf(v.w);
        tile[r][c0 + 0] = o.x; tile[r][c0 + 1] = o.y;
        tile[r][c0 + 2] = o.z; tile[r][c0 + 3] = o.w;
        *(ushort4*)&vbf[(long)b * 1048576 + (long)(l0 + r) * 1024 + e0 + c0] = o;
    }
    __syncthreads();
#pragma unroll
    for (int rr = 0; rr < 4; ++rr) {
        const int idx = rr * 256 + t;
        const int e   = idx >> 4;
        const int c4  = (idx & 15) * 4;
        ushort4 o;
        o.x = tile[c4 + 0][e]; o.y = tile[c4 + 1][e];
        o.z = tile[c4 + 2][e]; o.w = tile[c4 + 3][e];
        *(ushort4*)&vbfT[(long)b * 1048576 + (long)(e0 + e) * 1024 + l0 + c4] = o;
    }
}

// ---------------- query[b,n,d] = emb[max(node,0)][d] + bboxes . Wb[d,:] + bb[d]
__global__ __launch_bounds__(256) void build_query_k(
    const int* __restrict__ nodes, const float* __restrict__ bboxes,
    const float* __restrict__ emb, const float* __restrict__ Wb,
    const float* __restrict__ bb, float* __restrict__ query)
{
    const int blk = blockIdx.x;
    const int node = nodes[blk];
    const int idx = node < 0 ? 0 : node;
    const float4 bx = *(const float4*)&bboxes[blk * 4];
    const float* er = emb + (long)idx * 1024;
    for (int d = threadIdx.x; d < 1024; d += 256) {
        const float4 w = *(const float4*)&Wb[d * 4];
        query[(long)blk * 1024 + d] =
            er[d] + bb[d] + bx.x * w.x + bx.y * w.y + bx.z * w.z + bx.w * w.w;
    }
}

// ---------------- row softmax over 1024; fp32 in, bf16 out (padded 128 rows/b)
__global__ __launch_bounds__(256) void softmax_k(
    const float* __restrict__ sc, unsigned short* __restrict__ attn)
{
    __shared__ float red[4];
    const int blk = blockIdx.x;              // b*120 + r
    const int b = blk / 120, r = blk % 120;
    const float* p = sc + (long)blk * 1024;
    const int t = threadIdx.x;
    float4 v = *(const float4*)&p[t * 4];

    float m = fmaxf(fmaxf(v.x, v.y), fmaxf(v.z, v.w));
#pragma unroll
    for (int o = 32; o; o >>= 1) m = fmaxf(m, __shfl_xor(m, o));
    if ((t & 63) == 0) red[t >> 6] = m;
    __syncthreads();
    m = fmaxf(fmaxf(red[0], red[1]), fmaxf(red[2], red[3]));
    __syncthreads();

    v.x = __expf(v.x - m); v.y = __expf(v.y - m);
    v.z = __expf(v.z - m); v.w = __expf(v.w - m);
    float s = v.x + v.y + v.z + v.w;
#pragma unroll
    for (int o = 32; o; o >>= 1) s += __shfl_xor(s, o);
    if ((t & 63) == 0) red[t >> 6] = s;
    __syncthreads();
    s = red[0] + red[1] + red[2] + red[3];
    const float inv = 1.0f / s;
    ushort4 o;
    o.x = f2bf(v.x * inv); o.y = f2bf(v.y * inv);
    o.z = f2bf(v.z * inv); o.w = f2bf(v.w * inv);
    *(ushort4*)&attn[(long)(b * 128 + r) * 1024 + t * 4] = o;
}

// ---------------- edge head: one block per (b, i). thread = (j, c).
__global__ __launch_bounds__(320) void edge_k(
    const float* __restrict__ hi, const float* __restrict__ hj,
    const float* __restrict__ W2, const float* __restrict__ b2,
    float* __restrict__ out)
{
    const int b = blockIdx.x, i = blockIdx.y;
    const int t = threadIdx.x;
    __shared__ float hiS[256];
    __shared__ float hjS[15][257];
    __shared__ float w2S[18][257];
    const int j = t / 18, c = t % 18;
    float acc = 0.0f;

    for (int u0 = 0; u0 < 512; u0 += 256) {
        __syncthreads();
        if (t < 64) {
            float4 v = *(const float4*)&hi[(long)(b * 15 + i) * 512 + u0 + t * 4];
            hiS[t * 4 + 0] = v.x; hiS[t * 4 + 1] = v.y;
            hiS[t * 4 + 2] = v.z; hiS[t * 4 + 3] = v.w;
        }
        for (int x = t; x < 960; x += 320) {
            const int r = x >> 6, cc = (x & 63) * 4;
            float4 v = *(const float4*)&hj[(long)(b * 15 + r) * 512 + u0 + cc];
            hjS[r][cc + 0] = v.x; hjS[r][cc + 1] = v.y;
            hjS[r][cc + 2] = v.z; hjS[r][cc + 3] = v.w;
        }
        for (int x = t; x < 1152; x += 320) {
            const int r = x >> 6, cc = (x & 63) * 4;
            float4 v = *(const float4*)&W2[(long)r * 512 + u0 + cc];
            w2S[r][cc + 0] = v.x; w2S[r][cc + 1] = v.y;
            w2S[r][cc + 2] = v.z; w2S[r][cc + 3] = v.w;
        }
        __syncthreads();
        if (t < 270) {
            for (int u = 0; u < 256; ++u) {
                float p = hiS[u] + hjS[j][u];
                p = p > 0.0f ? p : 0.0f;
                acc += p * w2S[c][u];
            }
        }
    }
    if (t < 270)
        out[((long)(b * 15 + i) * 15 + j) * 18 + c] = acc + b2[c];
}

// ---------------- energy stage 1
__global__ __launch_bounds__(256) void energy1_k(
    const float* __restrict__ enr, const int* __restrict__ nodes,
    float* __restrict__ gfeat)
{
    const int b = blockIdx.y;
    const int e = blockIdx.x * 256 + threadIdx.x;
    int cnt = 0;
#pragma unroll
    for (int n = 0; n < 15; ++n) cnt += (nodes[b * 15 + n] != -1) ? 1 : 0;
    const float inv_valid = 1.0f / fmaxf((float)cnt, 1.0f);
    float s = 0.0f;
#pragma unroll
    for (int n = 0; n < 15; ++n) {
        const bool ok = nodes[b * 15 + n] != -1;
        s += ok ? enr[(long)(b * 15 + n) * 1024 + e] : 0.0f;
    }
    gfeat[b * 1024 + e] = s * inv_valid;
}

// ---------------- energy stage 2
__global__ __launch_bounds__(256) void energy2_k(
    const float* __restrict__ gfeat, const float* __restrict__ Wh1,
    const float* __restrict__ bh1, const float* __restrict__ Wh2,
    float* __restrict__ hidr)
{
    const int b  = blockIdx.y;
    const int u0 = blockIdx.x * 16;
    const int t = threadIdx.x;
    __shared__ float gf[1024];
    {
        float4 v = *(const float4*)&gfeat[b * 1024 + t * 4];
        gf[t * 4 + 0] = v.x; gf[t * 4 + 1] = v.y;
        gf[t * 4 + 2] = v.z; gf[t * 4 + 3] = v.w;
    }
    __syncthreads();
    const int wave = t >> 6, lane = t & 63;
#pragma unroll
    for (int r = 0; r < 4; ++r) {
        const int u = u0 + wave * 4 + r;
        float s = 0.0f;
#pragma unroll
        for (int e0 = 0; e0 < 1024; e0 += 64)
            s += gf[e0 + lane] * Wh1[(long)u * 1024 + e0 + lane];
#pragma unroll
        for (int o = 32; o; o >>= 1) s += __shfl_xor(s, o);
        if (lane == 0)
            hidr[b * 256 + u] = fmaxf(s + bh1[u], 0.0f) * Wh2[u];
    }
}

// ---------------- energy stage 3
__global__ __launch_bounds__(256) void energy3_k(
    const float* __restrict__ hidr, const float* __restrict__ bh2,
    float* __restrict__ out)
{
    const int b = blockIdx.x;
    const int t = threadIdx.x;
    __shared__ float red[4];
    float v = hidr[b * 256 + t];
#pragma unroll
    for (int o = 32; o; o >>= 1) v += __shfl_xor(v, o);
    if ((t & 63) == 0) red[t >> 6] = v;
    __syncthreads();
    if (t == 0) out[129600 + b] = red[0] + red[1] + red[2] + red[3] + bh2[0];
}

// ---------------------------------------------------------------------------
extern "C" void kernel_launch(void* const* d_in, const int* in_sizes, int n_in,
                              void* d_out, int out_size, void* d_ws, size_t ws_size,
                              hipStream_t stream)
{
    const float* visual = (const float*)d_in[0];
    const int*   nodes  = (const int*)  d_in[1];
    const float* bboxes = (const float*)d_in[2];
    const float* emb    = (const float*)d_in[3];
    const float* Wb     = (const float*)d_in[4];
    const float* bb     = (const float*)d_in[5];
    const float* Wq     = (const float*)d_in[6];
    const float* bq     = (const float*)d_in[7];
    const float* Wk     = (const float*)d_in[8];
    /* bk (d_in[9]) cancels in softmax */
    const float* Wv     = (const float*)d_in[10];
    const float* bv     = (const float*)d_in[11];
    const float* Wo     = (const float*)d_in[12];
    const float* bo     = (const float*)d_in[13];
    const float* W1     = (const float*)d_in[14];
    const float* b1     = (const float*)d_in[15];
    const float* W2     = (const float*)d_in[16];
    const float* b2     = (const float*)d_in[17];
    const float* Wh1    = (const float*)d_in[18];
    const float* bh1    = (const float*)d_in[19];
    const float* Wh2    = (const float*)d_in[20];
    const float* bh2    = (const float*)d_in[21];

    float* out = (float*)d_out;
    float* ws  = (float*)d_ws;

    // workspace layout (fp32 units)
    float* query  = ws;                       // 480*1024
    float* q      = ws + 491520;              // 480*1024
    float* scores = ws + 983040;              // 32*120*1024 fp32
    float* ctxf   = ws + 4915200;             // 32*120*1024 fp32
    float* ctx    = ws + 8847360;             // 480*1024
    float* enr    = ws + 9338880;             // 480*1024
    float* hi     = ws + 9830400;             // 480*512
    float* hj     = ws + 10076160;            // 480*512
    unsigned short* qW_bf   = (unsigned short*)(ws + 10321920); // 32*128*1024 bf16
    unsigned short* attn_bf = (unsigned short*)(ws + 12419072); // 32*128*1024 bf16
    unsigned short* v_bf    = (unsigned short*)(ws + 14516224); // 32*1024*1024 bf16
    unsigned short* v_bfT   = (unsigned short*)(ws + 31293440); // 32*1024*1024 bf16
    float* gfeat  = query;                    // alias (query dead after q GEMM)
    float* hidr   = query + 32768;            // alias

    const float inv_sqrt_hd = 0.08838834764831845f;  // 1/sqrt(128)
    const float* v_f = visual + 3 * 1048576;         // frame T-1; batch stride 4*1048576

    // 1) query build + v_f bf16 conversion (row + transposed)
    build_query_k<<<480, 256, 0, stream>>>(nodes, bboxes, emb, Wb, bb, query);
    cvt_k<<<dim3(16, 16, 32), 256, 0, stream>>>(v_f, v_bf, v_bfT);

    // 2) q = query @ Wq^T + bq            (480 x 1024, K=1024, fp32)
    gemm_k<64, 64, 16, 4, 4, true><<<dim3(16, 8, 1), 256, 0, stream>>>(
        query, Wq, bq, q, 480, 1024, 1024, 1024, 1024, 1024,
        0, 0, 0, 0, 1, 0, 0, 0, 0, 1.0f);

    // 3) qW_bf[b][(n,h)][e] = (q[b,n,h-slice] @ Wk[h-slice,:]) * inv_sqrt_hd
    //    batched z=(b,h): M=15, N=1024, K=128; bf16 output, padded 128 rows/b
    gemm_k<16, 64, 32, 1, 4, false, true><<<dim3(16, 1, 256), 256, 0, stream>>>(
        q, Wk, nullptr, qW_bf, 15, 1024, 128, 1024, 1024, 8192,
        15360, 0, 131072, 0, 8, 128, 131072, 1024, 0, inv_sqrt_hd);

    // 4) scores[b] = qW_bf[b] @ v_bf[b]^T   (MFMA, M=120 pad 128, N=1024, K=1024)
    bfgemm_k<<<dim3(8, 2, 32), 256, 0, stream>>>(
        qW_bf, v_bf, scores, 120, 131072, 1048576, 122880);

    // 5) softmax over l -> bf16 attn (padded 128 rows/b)
    softmax_k<<<3840, 256, 0, stream>>>(scores, attn_bf);

    // 6) ctxf[b] = attn[b] @ v_bfT[b]^T     (MFMA, K=1024 over tokens)
    bfgemm_k<<<dim3(8, 2, 32), 256, 0, stream>>>(
        attn_bf, v_bfT, ctxf, 120, 131072, 1048576, 122880);

    // 7) ctx[b,:,h] = ctxf[b,(:,h),:] @ Wv_h^T + bv_h   (fp32)
    gemm_k<16, 64, 32, 1, 4, true><<<dim3(2, 1, 256), 256, 0, stream>>>(
        ctxf, Wv, bv, ctx, 15, 128, 1024, 8192, 1024, 1024,
        122880, 0, 15360, 0, 8, 1024, 131072, 128, 128, 1.0f);

    // 8) enriched = ctx @ Wo^T + bo        (480 x 1024, K=1024, fp32)
    gemm_k<64, 64, 16, 4, 4, true><<<dim3(16, 8, 1), 256, 0, stream>>>(
        ctx, Wo, bo, enr, 480, 1024, 1024, 1024, 1024, 1024,
        0, 0, 0, 0, 1, 0, 0, 0, 0, 1.0f);

    // 9) hi = enr @ W1[:, :1024]^T + b1 ;  hj = enr @ W1[:, 1024:]^T  (fp32)
    gemm_k<64, 64, 16, 4, 4, true><<<dim3(8, 8, 1), 256, 0, stream>>>(
        enr, W1, b1, hi, 480, 512, 1024, 1024, 2048, 512,
        0, 0, 0, 0, 1, 0, 0, 0, 0, 1.0f);
    gemm_k<64, 64, 16, 4, 4, true><<<dim3(8, 8, 1), 256, 0, stream>>>(
        enr, W1 + 1024, nullptr, hj, 480, 512, 1024, 1024, 2048, 512,
        0, 0, 0, 0, 1, 0, 0, 0, 0, 1.0f);

    // 10) edge logits -> out[0 .. 129600)
    edge_k<<<dim3(32, 15, 1), 320, 0, stream>>>(hi, hj, W2, b2, out);

    // 11) energy -> out[129600 .. 129632)
    energy1_k<<<dim3(4, 32, 1), 256, 0, stream>>>(enr, nodes, gfeat);
    energy2_k<<<dim3(16, 32, 1), 256, 0, stream>>>(gfeat, Wh1, bh1, Wh2, hidr);
    energy3_k<<<32, 256, 0, stream>>>(hidr, bh2, out);
}